// Round 4
// baseline (283.501 us; speedup 1.0000x reference)
//
#include <hip/hip_runtime.h>
#include <math.h>

#define EPS 1e-8f
#define KT 32
#define KC1 2
#define NCHUNK 64   // edge chunks
#define NBG 8       // b-groups of 8 (B=64)

// ---------------------------------------------------------------------------
// K0: row norms. Blocks [0,S): rinv[s] = 1/(||S_s||+eps).
//     Blocks [S, S+B): Hs[b,:] = H[b,:]/(||H_b||+eps), gscale[b]=0.005*||G_b||
// ---------------------------------------------------------------------------
__global__ void k_norms(const float* __restrict__ Sg, const float* __restrict__ Hg,
                        const float* __restrict__ Gg, float* __restrict__ rinv,
                        float* __restrict__ Hs, float* __restrict__ gscale,
                        int Srows, int Fdim, int Bdim) {
    __shared__ float wsum[4];
    __shared__ float wsum2[4];
    __shared__ float bc0;
    int row = blockIdx.x;
    int tid = threadIdx.x;
    int lane = tid & 63, wv = tid >> 6;

    if (row < Srows) {
        const float* p = Sg + (size_t)row * Fdim;
        float acc = 0.f;
        for (int i = tid; i < Fdim; i += 256) { float v = p[i]; acc += v * v; }
        for (int off = 32; off > 0; off >>= 1) acc += __shfl_down(acc, off, 64);
        if (lane == 0) wsum[wv] = acc;
        __syncthreads();
        if (tid == 0) {
            float t = wsum[0] + wsum[1] + wsum[2] + wsum[3];
            rinv[row] = 1.0f / (sqrtf(t) + EPS);
        }
    } else {
        int b = row - Srows;
        if (b >= Bdim) return;
        const float* ph = Hg + (size_t)b * Fdim;
        const float* pg = Gg + (size_t)b * Fdim;
        float ah = 0.f, ag = 0.f;
        for (int i = tid; i < Fdim; i += 256) {
            float h = ph[i]; ah += h * h;
            float g = pg[i]; ag += g * g;
        }
        for (int off = 32; off > 0; off >>= 1) {
            ah += __shfl_down(ah, off, 64);
            ag += __shfl_down(ag, off, 64);
        }
        if (lane == 0) { wsum[wv] = ah; wsum2[wv] = ag; }
        __syncthreads();
        if (tid == 0) {
            float th = wsum[0] + wsum[1] + wsum[2] + wsum[3];
            float tg = wsum2[0] + wsum2[1] + wsum2[2] + wsum2[3];
            bc0 = 1.0f / (sqrtf(th) + EPS);
            gscale[b] = 0.005f * sqrtf(tg);
        }
        __syncthreads();
        float hn = bc0;
        float* dst = Hs + (size_t)b * Fdim;
        for (int i = tid; i < Fdim; i += 256) dst[i] = ph[i] * hn;
    }
}

// ---------------------------------------------------------------------------
// K1: GEMM1  Pt_part[kc][s][b] = rinv[s] * sum_{k in chunk kc} Hs[b,k]*Sg[s,k]
// Tile 64b x 32s, KT=32, split-K KC1=2. Grid (S/32, KC1) = 512 blocks.
// tx(16)->b (float4 of 4), ty(16)->s (2 each). s-major coalesced float4 store.
// ---------------------------------------------------------------------------
__global__ __launch_bounds__(256) void k_gemm1(
        const float* __restrict__ Hs, const float* __restrict__ Sg,
        const float* __restrict__ rinv, float* __restrict__ Pt_part,
        int Srows, int Fdim, int kchunk) {
    __shared__ float lA[KT][68];   // [k][b]  (stride 68 floats = 272B, 16B mult)
    __shared__ float lB[KT][36];   // [k][s]
    int tid = threadIdx.x;
    int tx = tid & 15;          // b: 4 each
    int ty = tid >> 4;          // s: 2 each
    int s0 = blockIdx.x * 32;
    int kb = blockIdx.y * kchunk;

    float4 acc0 = {0.f, 0.f, 0.f, 0.f};
    float4 acc1 = {0.f, 0.f, 0.f, 0.f};

    for (int kt = 0; kt < kchunk; kt += KT) {
        #pragma unroll
        for (int i = 0; i < 8; i++) {           // 64b x 32k
            int idx = tid + i * 256;
            int c = idx & 31, r = idx >> 5;
            lA[c][r] = Hs[(size_t)r * Fdim + kb + kt + c];
        }
        #pragma unroll
        for (int i = 0; i < 4; i++) {           // 32s x 32k
            int idx = tid + i * 256;
            int c = idx & 31, r = idx >> 5;
            lB[c][r] = Sg[(size_t)(s0 + r) * Fdim + kb + kt + c];
        }
        __syncthreads();
        #pragma unroll
        for (int k = 0; k < KT; k++) {
            float4 hv = *(const float4*)&lA[k][tx * 4];
            float2 sv = *(const float2*)&lB[k][ty * 2];
            acc0.x += sv.x * hv.x; acc0.y += sv.x * hv.y;
            acc0.z += sv.x * hv.z; acc0.w += sv.x * hv.w;
            acc1.x += sv.y * hv.x; acc1.y += sv.y * hv.y;
            acc1.z += sv.y * hv.z; acc1.w += sv.y * hv.w;
        }
        __syncthreads();
    }
    int sa = s0 + ty * 2;
    float r0 = rinv[sa], r1 = rinv[sa + 1];
    float4 o0, o1;
    o0.x = acc0.x * r0; o0.y = acc0.y * r0; o0.z = acc0.z * r0; o0.w = acc0.w * r0;
    o1.x = acc1.x * r1; o1.y = acc1.y * r1; o1.z = acc1.z * r1; o1.w = acc1.w * r1;
    size_t base = (size_t)blockIdx.y * Srows;
    *(float4*)&Pt_part[(base + sa) * 64 + tx * 4]     = o0;
    *(float4*)&Pt_part[(base + sa + 1) * 64 + tx * 4] = o1;
}

// combine split-K halves: Pt = Pt_part[0] + Pt_part[1]   (n floats per half)
__global__ void k_combine(const float* __restrict__ Pp, float* __restrict__ Pt, int n) {
    int i = blockIdx.x * 256 + threadIdx.x;        // float4 index
    if (i >= n / 4) return;
    const float4* a = (const float4*)Pp;
    const float4* b = (const float4*)(Pp + n);
    float4 x = a[i], y = b[i];
    x.x += y.x; x.y += y.y; x.z += y.z; x.w += y.w;
    ((float4*)Pt)[i] = x;
}

// ---------------------------------------------------------------------------
// K2: direct edge aggregation.
// Grid (NCHUNK, NBG). Block (ch, bg) handles 8 b-values bg*8..bg*8+7 and
// edges [ch*chunkSize, ...). LDS accum bins[D][8]; bg==0 also accumulates
// colw[d] = sum w. Per edge-group: coalesced 32B Pt gather + 8 LDS atomics
// at d*8+bi (conflict-free within group).
// ---------------------------------------------------------------------------
__global__ __launch_bounds__(256) void k_agg(
        const float* __restrict__ Pt, const float* __restrict__ ew,
        const int* __restrict__ ed, const int* __restrict__ es,
        float* __restrict__ part2, float* __restrict__ colw,
        int E, int chunkSize, int Dd) {
    __shared__ float bins[1024 * 8];
    __shared__ float cw[1024];
    int tid = threadIdx.x;
    int ch = blockIdx.x, bg = blockIdx.y;
    for (int i = tid; i < Dd * 8; i += 256) bins[i] = 0.f;
    if (bg == 0) for (int i = tid; i < Dd; i += 256) cw[i] = 0.f;
    __syncthreads();

    int e0 = ch * chunkSize;
    int e1 = min(e0 + chunkSize, E);
    int g  = tid >> 3;     // 0..31: edge slot within block-iteration
    int bi = tid & 7;
    int b  = bg * 8 + bi;
    bool docw = (bg == 0) && (bi == 0);

    int e = e0 + g;
    // main loop: 4 edges in flight per lane
    for (; e + 96 < e1; e += 128) {
        int s0_ = es[e],       s1_ = es[e + 32],   s2_ = es[e + 64],   s3_ = es[e + 96];
        int d0_ = ed[e],       d1_ = ed[e + 32],   d2_ = ed[e + 64],   d3_ = ed[e + 96];
        float w0 = ew[e],      w1 = ew[e + 32],    w2 = ew[e + 64],    w3 = ew[e + 96];
        float q0 = Pt[(size_t)s0_ * 64 + b];
        float q1 = Pt[(size_t)s1_ * 64 + b];
        float q2 = Pt[(size_t)s2_ * 64 + b];
        float q3 = Pt[(size_t)s3_ * 64 + b];
        atomicAdd(&bins[d0_ * 8 + bi], w0 * q0);
        atomicAdd(&bins[d1_ * 8 + bi], w1 * q1);
        atomicAdd(&bins[d2_ * 8 + bi], w2 * q2);
        atomicAdd(&bins[d3_ * 8 + bi], w3 * q3);
        if (docw) {
            atomicAdd(&cw[d0_], w0); atomicAdd(&cw[d1_], w1);
            atomicAdd(&cw[d2_], w2); atomicAdd(&cw[d3_], w3);
        }
    }
    for (; e < e1; e += 32) {
        int s = es[e];
        int d = ed[e];
        float w = ew[e];
        float q = Pt[(size_t)s * 64 + b];
        atomicAdd(&bins[d * 8 + bi], w * q);
        if (docw) atomicAdd(&cw[d], w);
    }
    __syncthreads();
    float* dst = part2 + ((size_t)bg * NCHUNK + ch) * (Dd * 8);
    for (int i = tid; i < Dd * 8; i += 256) dst[i] = bins[i];
    if (bg == 0) {
        float* cdst = colw + (size_t)ch * Dd;
        for (int i = tid; i < Dd; i += 256) cdst[i] = cw[i];
    }
}

// colsum[d] = sum_ch colw[ch][d]
__global__ void k_colsum(const float* __restrict__ colw, float* __restrict__ colsum,
                         int Dd) {
    int d = blockIdx.x * 256 + threadIdx.x;
    if (d >= Dd) return;
    float s = 0.f;
    #pragma unroll 8
    for (int ch = 0; ch < NCHUNK; ch++)
        s += colw[(size_t)ch * Dd + d];
    colsum[d] = s;
}

// ---------------------------------------------------------------------------
// K3: epilogue  out[b,d] = gscale[b] * (sum_ch part2[bg][ch][d][bi] + colsum[d])
// ---------------------------------------------------------------------------
__global__ void k_epi(const float* __restrict__ part2, const float* __restrict__ colsum,
                      const float* __restrict__ gscale, float* __restrict__ out,
                      int Dd, int Bdim) {
    int idx = blockIdx.x * 256 + threadIdx.x;
    if (idx >= Bdim * Dd) return;
    int b = idx / Dd;
    int d = idx - b * Dd;
    int bg = b >> 3, bi = b & 7;
    const float* src = part2 + (size_t)bg * NCHUNK * (Dd * 8) + d * 8 + bi;
    float s = 0.f;
    #pragma unroll 8
    for (int ch = 0; ch < NCHUNK; ch++)
        s += src[(size_t)ch * (Dd * 8)];
    out[idx] = gscale[b] * (s + colsum[d]);
}

extern "C" void kernel_launch(void* const* d_in, const int* in_sizes, int n_in,
                              void* d_out, int out_size, void* d_ws, size_t ws_size,
                              hipStream_t stream) {
    const float* H  = (const float*)d_in[0];
    const float* G  = (const float*)d_in[1];
    const float* Sg = (const float*)d_in[2];
    const float* ew = (const float*)d_in[3];
    const int*   ed = (const int*)d_in[4];
    const int*   es = (const int*)d_in[5];

    const int B = 64;
    const int F = in_sizes[0] / B;        // 512
    const int S = in_sizes[2] / F;        // 8192
    const int E = in_sizes[3];            // 500000
    const int D = out_size / B;           // 1024
    float* out = (float*)d_out;

    // workspace layout (floats); every buffer fully written before read
    float* ws = (float*)d_ws;
    size_t off = 0;
    float* rinv    = ws + off; off += (size_t)S;                    // 8192
    float* Hs      = ws + off; off += (size_t)B * F;                // 32768
    float* gscale  = ws + off; off += 256;
    float* colsum  = ws + off; off += (size_t)D;
    float* Pt_part = ws + off; off += (size_t)KC1 * S * B;          // 1.05M
    float* Pt      = ws + off; off += (size_t)S * B;                // 524288
    float* part2   = ws + off; off += (size_t)NBG * NCHUNK * D * 8; // 4.19M
    float* colw    = ws + off; off += (size_t)NCHUNK * D;           // 65536

    k_norms<<<S + B, 256, 0, stream>>>(Sg, H, G, rinv, Hs, gscale, S, F, B);
    dim3 g1(S / 32, KC1);
    k_gemm1<<<g1, 256, 0, stream>>>(Hs, Sg, rinv, Pt_part, S, F, F / KC1);
    int nPt = S * B;
    k_combine<<<(nPt / 4 + 255) / 256, 256, 0, stream>>>(Pt_part, Pt, nPt);
    int chunkSize = (E + NCHUNK - 1) / NCHUNK;
    dim3 ga(NCHUNK, NBG);
    k_agg<<<ga, 256, 0, stream>>>(Pt, ew, ed, es, part2, colw, E, chunkSize, D);
    k_colsum<<<(D + 255) / 256, 256, 0, stream>>>(colw, colsum, D);
    k_epi<<<(B * D + 255) / 256, 256, 0, stream>>>(part2, colsum, gscale, out, D, B);
}